// Round 3
// baseline (967.382 us; speedup 1.0000x reference)
//
#include <hip/hip_runtime.h>
#include <math.h>

typedef __attribute__((ext_vector_type(8))) short bf16x8;   // 8 bf16 in 4 VGPRs
typedef __attribute__((ext_vector_type(4))) float f32x4;
typedef unsigned short u16;

#define PS_LD 136   // LDS staging row stride (u16): 272B = 16B-aligned, low conflicts

__device__ __forceinline__ u16 f2bf(float f) {
  unsigned u = __float_as_uint(f);
  return (u16)((u + 0x7FFFu + ((u >> 16) & 1u)) >> 16);   // RNE
}
__device__ __forceinline__ float bf2f(u16 h) {
  return __uint_as_float(((unsigned)h) << 16);
}

__device__ __forceinline__ void gload16(const u16* g, void* lds) {
  __builtin_amdgcn_global_load_lds(
      (const __attribute__((address_space(1))) unsigned int*)g,
      (__attribute__((address_space(3))) unsigned int*)lds, 16, 0, 0);
}

// ---------------------------------------------------------------------------
// MFMA core: 128x128 tile, BK=32, 256 threads (4 waves = 2x2 quadrants of
// 4x4 16x16x32 fragments). A,B pre-offset to (m0,0)/(n0,0); strides in elems;
// K multiple of 32; all addresses in-bounds (padded buffers).
// ---------------------------------------------------------------------------
__device__ __forceinline__ void mfma_core(
    const u16* __restrict__ A, int lda,
    const u16* __restrict__ B, int ldb,
    int K, f32x4 (&acc)[4][4], u16* As, u16* Bs)
{
  const int tid = threadIdx.x;
  const int l = tid & 63, w = tid >> 6;
  const int srow = w * 16 + (l >> 2);
  const int kel  = (l & 3) * 8;
  char* AsB = (char*)As + w * 1024;
  char* BsB = (char*)Bs + w * 1024;
  const u16* Ap  = A + (size_t)srow * lda + kel;
  const u16* Ap2 = A + (size_t)(srow + 64) * lda + kel;
  const u16* Bp  = B + (size_t)srow * ldb + kel;
  const u16* Bp2 = B + (size_t)(srow + 64) * ldb + kel;
  const int wm = w >> 1, wn = w & 1;
  const int aoff = (wm * 64 + (l & 15)) * 32 + (l >> 4) * 8;
  const int boff = (wn * 64 + (l & 15)) * 32 + (l >> 4) * 8;
  for (int kb = 0; kb < K; kb += 32) {
    __syncthreads();
    gload16(Ap + kb,  AsB);
    gload16(Ap2 + kb, AsB + 4096);
    gload16(Bp + kb,  BsB);
    gload16(Bp2 + kb, BsB + 4096);
    __syncthreads();
    bf16x8 av[4], bv[4];
#pragma unroll
    for (int i = 0; i < 4; ++i) {
      av[i] = *(const bf16x8*)(As + aoff + i * 16 * 32);
      bv[i] = *(const bf16x8*)(Bs + boff + i * 16 * 32);
    }
#pragma unroll
    for (int i = 0; i < 4; ++i)
#pragma unroll
      for (int j = 0; j < 4; ++j)
        acc[i][j] = __builtin_amdgcn_mfma_f32_16x16x32_bf16(av[i], bv[j], acc[i][j], 0, 0, 0);
  }
}

// Stage acc (bf16, scaled) into Ps[128][PS_LD]. Aliases As/Bs (barriers guard).
__device__ __forceinline__ void stage_tile(const f32x4 (&acc)[4][4], float scale,
                                           u16* Ps)
{
  const int tid = threadIdx.x, l = tid & 63, w = tid >> 6, wm = w >> 1, wn = w & 1;
  __syncthreads();
#pragma unroll
  for (int i = 0; i < 4; ++i) {
    const int row0 = wm * 64 + i * 16 + (l >> 4) * 4;
#pragma unroll
    for (int j = 0; j < 4; ++j) {
      const int col = wn * 64 + j * 16 + (l & 15);
#pragma unroll
      for (int r = 0; r < 4; ++r)
        Ps[(row0 + r) * PS_LD + col] = f2bf(acc[i][j][r] * scale);
    }
  }
  __syncthreads();
}

// ---------------------------------------------------------------------------
// f32 -> bf16 pad-copy
// ---------------------------------------------------------------------------
__global__ __launch_bounds__(256) void k_padcvt(
    const float* __restrict__ src, u16* __restrict__ dst,
    int srcR, int dstR, int C, long long dstStride, long long dstOff, long long total)
{
  long long idx = (long long)blockIdx.x * 256 + threadIdx.x;
  if (idx >= total) return;
  long long per = (long long)dstR * C;
  int g  = (int)(idx / per);
  int r2 = (int)(idx % per);
  int rr = r2 / C, c = r2 - rr * C;
  float v = (rr < srcR) ? src[((long long)g * srcR + rr) * C + c] : 0.f;
  dst[g * dstStride + dstOff + (long long)rr * C + c] = f2bf(v);
}

// Kt[h][o(1024)][NB] = Wk[h] x embA^T
__global__ __launch_bounds__(256) void k_kt(const u16* __restrict__ embA,
    const u16* __restrict__ WkB, u16* __restrict__ Kt, int b0, int NB)
{
  __shared__ u16 smem[128 * PS_LD];
  u16* As = smem; u16* Bs = smem + 4096; u16* Ps = smem;
  const int h = blockIdx.z;
  const int m0 = blockIdx.y * 128, n0 = blockIdx.x * 128;
  const u16* A = WkB + (size_t)h * 1024 * 960 + (size_t)m0 * 960;
  const u16* B = embA + (size_t)(b0 * 224 + n0) * 960;
  f32x4 acc[4][4] = {};
  mfma_core(A, 960, B, 960, 960, acc, As, Bs);
  stage_tile(acc, 1.f, Ps);
  const int tid = threadIdx.x, row = tid >> 1, half = tid & 1;
  u16* dst = Kt + (size_t)h * 1024 * NB + (size_t)(m0 + row) * NB + n0 + half * 64;
  const u16* srcp = Ps + row * PS_LD + half * 64;
#pragma unroll
  for (int q = 0; q < 8; ++q)
    *(uint4*)(dst + q * 8) = *(const uint4*)(srcp + q * 8);
}

// V[lb][h][n(256 pad)][o(1024)] = embA x Wv[h]^T
__global__ __launch_bounds__(256) void k_v(const u16* __restrict__ embA,
    const u16* __restrict__ WvB, u16* __restrict__ V, int b0, int NB)
{
  __shared__ u16 smem[128 * PS_LD];
  u16* As = smem; u16* Bs = smem + 4096; u16* Ps = smem;
  const int h = blockIdx.z;
  const int m0 = blockIdx.y * 128, n0 = blockIdx.x * 128;
  const u16* A = embA + (size_t)(b0 * 224 + m0) * 960;
  const u16* B = WvB + (size_t)h * 1024 * 960 + (size_t)n0 * 960;
  f32x4 acc[4][4] = {};
  mfma_core(A, 960, B, 960, 960, acc, As, Bs);
  stage_tile(acc, 1.f, Ps);
  const int tid = threadIdx.x, row = tid >> 1, half = tid & 1;
  const int t = m0 + row, lb = t / 224, n = t - lb * 224;
  u16* dst = V + ((size_t)(lb * 4 + h) * 256 + n) * 1024 + n0 + half * 64;
  const u16* srcp = Ps + row * PS_LD + half * 64;
#pragma unroll
  for (int q = 0; q < 8; ++q)
    *(uint4*)(dst + q * 8) = *(const uint4*)(srcp + q * 8);
}

// Qt[h][ccat(1024)][NB] = Wq_br[h] x emb_br^T   (emb slices read from embA)
__global__ __launch_bounds__(256) void k_q(const u16* __restrict__ embA,
    const u16* __restrict__ WqB, u16* __restrict__ Qt, int b0, int NB)
{
  __shared__ u16 smem[128 * PS_LD];
  u16* As = smem; u16* Bs = smem + 4096; u16* Ps = smem;
  const int h = blockIdx.z;
  const int y = blockIdx.y;
  const int br = (y == 0) ? 0 : (y == 1) ? 1 : (y < 4) ? 2 : 3;
  const int mt = (y <= 1) ? 0 : (y < 4) ? (y - 2) : (y - 4);
  const int Ci = 64 << br;
  const int coff = (br == 0) ? 0 : (br == 1) ? 64 : (br == 2) ? 192 : 448;
  const int wqo = (br == 0) ? 0 : (br == 1) ? 8192 : (br == 2) ? 24576 : 90112;
  const int n0 = blockIdx.x * 128;
  const u16* A = WqB + (size_t)h * 352256 + wqo + (size_t)mt * 128 * Ci;
  const u16* B = embA + (size_t)(b0 * 224 + n0) * 960 + coff;
  f32x4 acc[4][4] = {};
  mfma_core(A, Ci, B, 960, Ci, acc, As, Bs);
  stage_tile(acc, 1.f, Ps);
  const int tid = threadIdx.x, row = tid >> 1, half = tid & 1;
  const int lr = mt * 128 + row;
  if (lr < Ci) {
    u16* dst = Qt + (size_t)h * 1024 * NB + (size_t)(coff + lr) * NB + n0 + half * 64;
    const u16* srcp = Ps + row * PS_LD + half * 64;
#pragma unroll
    for (int q = 0; q < 8; ++q)
      *(uint4*)(dst + q * 8) = *(const uint4*)(srcp + q * 8);
  }
}

// S[z][c(1024)][o(1024)] = (Qt . Kt^T)/sqrt(960), + per-(z,branch) sum/sumsq
__global__ __launch_bounds__(256) void k_s(const u16* __restrict__ Qt,
    const u16* __restrict__ Kt, u16* __restrict__ S, float* __restrict__ stats,
    int NB)
{
  __shared__ u16 smem[128 * PS_LD];
  __shared__ float sb[8];
  u16* As = smem; u16* Bs = smem + 4096; u16* Ps = smem;
  const int tid = threadIdx.x;
  if (tid < 8) sb[tid] = 0.f;
  const int z = blockIdx.z;           // lb*4 + h
  const int lb = z >> 2, h = z & 3;
  const int m0 = blockIdx.y * 128, n0 = blockIdx.x * 128;
  const u16* A = Qt + (size_t)h * 1024 * NB + (size_t)m0 * NB + lb * 224;
  const u16* B = Kt + (size_t)h * 1024 * NB + (size_t)n0 * NB + lb * 224;
  f32x4 acc[4][4] = {};
  mfma_core(A, NB, B, NB, 224, acc, As, Bs);
  const int l = tid & 63, w = tid >> 6, wm = w >> 1;
  const float scale = 0.03227486121839514f;   // 1/sqrt(960)
#pragma unroll
  for (int i = 0; i < 4; ++i) {
    const int gm0 = m0 + wm * 64 + i * 16 + (l >> 4) * 4;
    const int br = (gm0 < 64) ? 0 : (gm0 < 192) ? 1 : (gm0 < 448) ? 2 : 3;
    float sv = 0.f, qv = 0.f;
#pragma unroll
    for (int j = 0; j < 4; ++j)
#pragma unroll
      for (int r = 0; r < 4; ++r) {
        const float v = acc[i][j][r] * scale;
        sv += v; qv += v * v;
      }
    if (gm0 < 960) {
      atomicAdd(&sb[br * 2], sv);
      atomicAdd(&sb[br * 2 + 1], qv);
    }
  }
  stage_tile(acc, scale, Ps);
  const int row = tid >> 1, half = tid & 1;
  u16* dst = S + (size_t)z * 1024 * 1024 + (size_t)(m0 + row) * 1024 + n0 + half * 64;
  const u16* srcp = Ps + row * PS_LD + half * 64;
#pragma unroll
  for (int q = 0; q < 8; ++q)
    *(uint4*)(dst + q * 8) = *(const uint4*)(srcp + q * 8);
  if (tid < 8) atomicAdd(stats + (size_t)z * 8 + tid, sb[tid]);
}

// Row softmax with InstanceNorm temperature (mean cancels; rs = rsqrt(var+eps)).
__global__ __launch_bounds__(256) void k_sm(u16* __restrict__ S,
                                            const float* __restrict__ stats)
{
  const int tid = threadIdx.x, l = tid & 63;
  const int ri = blockIdx.x * 4 + (tid >> 6);
  const int z = ri / 960, c = ri - (ri / 960) * 960;
  const int br = (c < 64) ? 0 : (c < 192) ? 1 : (c < 448) ? 2 : 3;
  const float cnt = (float)(64 << br) * 960.f;
  const float s0 = stats[z * 8 + br * 2], s1 = stats[z * 8 + br * 2 + 1];
  const float mean = s0 / cnt;
  const float var = s1 / cnt - mean * mean;
  const float rs = rsqrtf(var + 1e-5f);
  u16* row = S + (size_t)(z * 1024 + c) * 1024;
  const bool ok1 = (l < 56);
  bf16x8 v0 = *(const bf16x8*)(row + l * 8);
  bf16x8 v1 = *(const bf16x8*)(row + 512 + l * 8);
  float x0[8], x1[8];
#pragma unroll
  for (int i = 0; i < 8; ++i) x0[i] = bf2f((u16)v0[i]) * rs;
#pragma unroll
  for (int i = 0; i < 8; ++i) x1[i] = bf2f((u16)v1[i]) * rs;
  float m = -1e30f;
#pragma unroll
  for (int i = 0; i < 8; ++i) m = fmaxf(m, x0[i]);
  if (ok1) {
#pragma unroll
    for (int i = 0; i < 8; ++i) m = fmaxf(m, x1[i]);
  }
#pragma unroll
  for (int off = 32; off > 0; off >>= 1) m = fmaxf(m, __shfl_xor(m, off, 64));
  float e0[8], e1[8], s = 0.f;
#pragma unroll
  for (int i = 0; i < 8; ++i) { e0[i] = __expf(x0[i] - m); s += e0[i]; }
#pragma unroll
  for (int i = 0; i < 8; ++i) { e1[i] = ok1 ? __expf(x1[i] - m) : 0.f; s += e1[i]; }
#pragma unroll
  for (int off = 32; off > 0; off >>= 1) s += __shfl_xor(s, off, 64);
  const float inv = 1.f / s;
  bf16x8 o0, o1;
#pragma unroll
  for (int i = 0; i < 8; ++i) o0[i] = (short)f2bf(e0[i] * inv);
#pragma unroll
  for (int i = 0; i < 8; ++i) o1[i] = (short)f2bf(e1[i] * inv);
  *(bf16x8*)(row + l * 8) = o0;
  if (ok1) *(bf16x8*)(row + 512 + l * 8) = o1;
}

// ctxh[z][n(224)][c(1024)] = V[z] . P[z]^T   (bf16 partial per head)
__global__ __launch_bounds__(256) void k_pv(const u16* __restrict__ V,
    const u16* __restrict__ S, u16* __restrict__ ctxh)
{
  __shared__ u16 smem[128 * PS_LD];
  u16* As = smem; u16* Bs = smem + 4096; u16* Ps = smem;
  const int z = blockIdx.z;
  const int m0 = blockIdx.y * 128, n0 = blockIdx.x * 128;
  const u16* A = V + (size_t)z * 256 * 1024 + (size_t)m0 * 1024;
  const u16* B = S + (size_t)z * 1024 * 1024 + (size_t)n0 * 1024;
  f32x4 acc[4][4] = {};
  mfma_core(A, 1024, B, 1024, 960, acc, As, Bs);
  stage_tile(acc, 1.f, Ps);
  const int tid = threadIdx.x, row = tid >> 1, half = tid & 1;
  const int t = m0 + row;
  if (t < 224) {
    u16* dst = ctxh + ((size_t)z * 224 + t) * 1024 + n0 + half * 64;
    const u16* srcp = Ps + row * PS_LD + half * 64;
#pragma unroll
    for (int q = 0; q < 8; ++q)
      *(uint4*)(dst + q * 8) = *(const uint4*)(srcp + q * 8);
  }
}

// ctx[lb][n][c] = bf16( 0.25 * sum_h ctxh[lb*4+h][n][c] )   (8 elems/thread)
__global__ __launch_bounds__(256) void k_ctxred(const u16* __restrict__ ctxh,
    u16* __restrict__ ctx, int Bc)
{
  const long long i8 = ((long long)blockIdx.x * 256 + threadIdx.x) * 8;
  if (i8 >= (long long)Bc * 229376) return;
  const int lb = (int)(i8 / 229376);
  const int off = (int)(i8 - (long long)lb * 229376);
  const u16* p = ctxh + (size_t)lb * 4 * 229376 + off;
  float s[8] = {};
#pragma unroll
  for (int h = 0; h < 4; ++h) {
    bf16x8 v = *(const bf16x8*)(p + (size_t)h * 229376);
#pragma unroll
    for (int i = 0; i < 8; ++i) s[i] += bf2f((u16)v[i]);
  }
  bf16x8 o;
#pragma unroll
  for (int i = 0; i < 8; ++i) o[i] = (short)f2bf(s[i] * 0.25f);
  *(bf16x8*)(ctx + (size_t)lb * 262144 + off) = o;
}

// O_br[b][n][c'] = ctx[b][n, coff:coff+Ci] . Wo_br^T   (f32 to d_out)
__global__ __launch_bounds__(256) void k_o(const u16* __restrict__ ctx,
    const u16* __restrict__ WoB, float* __restrict__ out, int b0)
{
  __shared__ u16 smem[128 * PS_LD];
  u16* As = smem; u16* Bs = smem + 4096;
  const int lb = blockIdx.z;
  const int x = blockIdx.x;
  const int br = (x == 0) ? 0 : (x == 1) ? 1 : (x < 4) ? 2 : 3;
  const int nt = (x <= 1) ? 0 : (x < 4) ? (x - 2) : (x - 4);
  const int Ci = 64 << br;
  const int coff = (br == 0) ? 0 : (br == 1) ? 64 : (br == 2) ? 192 : 448;
  const int woo = (br == 0) ? 0 : (br == 1) ? 8192 : (br == 2) ? 24576 : 90112;
  const long long ob = (br == 0) ? 0LL : (br == 1) ? 401408LL : (br == 2) ? 1204224LL : 2809856LL;
  const int m0 = blockIdx.y * 128;
  const u16* A = ctx + (size_t)lb * 262144 + (size_t)m0 * 1024 + coff;
  const u16* B = WoB + woo + (size_t)nt * 128 * Ci;
  f32x4 acc[4][4] = {};
  mfma_core(A, 1024, B, Ci, Ci, acc, As, Bs);
  const int tid = threadIdx.x, l = tid & 63, w = tid >> 6, wm = w >> 1, wn = w & 1;
  float* O = out + ob;
  const int gb = b0 + lb;
#pragma unroll
  for (int i = 0; i < 4; ++i) {
    const int row0 = m0 + wm * 64 + i * 16 + (l >> 4) * 4;
#pragma unroll
    for (int j = 0; j < 4; ++j) {
      const int cg = nt * 128 + wn * 64 + j * 16 + (l & 15);
#pragma unroll
      for (int r = 0; r < 4; ++r) {
        const int row = row0 + r;
        if (row < 196 && cg < Ci)
          O[((size_t)gb * 196 + row) * Ci + cg] = acc[i][j][r];
      }
    }
  }
}

// ---------------------------------------------------------------------------
extern "C" void kernel_launch(void* const* d_in, const int* in_sizes, int n_in,
                              void* d_out, int out_size, void* d_ws, size_t ws_size,
                              hipStream_t stream)
{
  const float* e1  = (const float*)d_in[0];
  const float* e2  = (const float*)d_in[1];
  const float* e3  = (const float*)d_in[2];
  const float* e4  = (const float*)d_in[3];
  const float* eall = (const float*)d_in[4];
  const float* Wq1 = (const float*)d_in[5];
  const float* Wq2 = (const float*)d_in[6];
  const float* Wq3 = (const float*)d_in[7];
  const float* Wq4 = (const float*)d_in[8];
  const float* Wk  = (const float*)d_in[9];
  const float* Wv  = (const float*)d_in[10];
  const float* Wo1 = (const float*)d_in[11];
  const float* Wo2 = (const float*)d_in[12];
  const float* Wo3 = (const float*)d_in[13];
  const float* Wo4 = (const float*)d_in[14];
  float* out = (float*)d_out;
  (void)e1; (void)e2; (void)e3; (void)e4;

  char* p = (char*)d_ws;
  auto alloc = [&](size_t bytes) -> void* {
    void* r = p; p += (bytes + 255) & ~(size_t)255; return r;
  };
  u16* embA = (u16*)alloc((size_t)7168 * 960 * 2);
  u16* WkB  = (u16*)alloc((size_t)4 * 1024 * 960 * 2);
  u16* WvB  = (u16*)alloc((size_t)4 * 1024 * 960 * 2);
  u16* WqB  = (u16*)alloc((size_t)4 * 352256 * 2);
  u16* WoB  = (u16*)alloc((size_t)352256 * 2);
  const size_t persist = (size_t)(p - (char*)d_ws);
  // per-batch: Kt+Qt (2*4*1024*224*2) + V (4*256*1024*2) + S (4*1024*1024*2)
  //          + ctxh bf16 (4*224*1024*2) + ctx (256*1024*2) + stats
  const size_t perBatch = (size_t)(1835008 + 1048576 + 4194304 + 917504 + 262144) * 2 + 512;
  int Bc = 4;
  if      (persist + 32 * perBatch <= ws_size) Bc = 32;
  else if (persist + 16 * perBatch <= ws_size) Bc = 16;
  else if (persist +  8 * perBatch <= ws_size) Bc = 8;
  const int NB = Bc * 224;

  u16* Kt  = (u16*)alloc((size_t)4 * 1024 * NB * 2);
  u16* Qt  = (u16*)alloc((size_t)4 * 1024 * NB * 2);
  u16* V   = (u16*)alloc((size_t)Bc * 4 * 256 * 1024 * 2);
  u16* S   = (u16*)alloc((size_t)Bc * 4 * 1024 * 1024 * 2);
  u16* ctxh = (u16*)alloc((size_t)Bc * 4 * 229376 * 2);
  u16* ctx = (u16*)alloc((size_t)Bc * 262144 * 2);
  float* stats = (float*)alloc((size_t)Bc * 32 * 4);

  const dim3 blk(256);
  auto cvt = [&](const float* src, u16* dst, int srcR, int dstR, int C,
                 long long stride, long long off, int g) {
    long long total = (long long)g * dstR * C;
    int gridc = (int)((total + 255) / 256);
    k_padcvt<<<dim3(gridc), blk, 0, stream>>>(src, dst, srcR, dstR, C, stride, off, total);
  };
  cvt(eall, embA, 196, 224, 960, (long long)224 * 960, 0, 32);
  cvt(Wk, WkB, 960, 1024, 960, (long long)1024 * 960, 0, 4);
  cvt(Wv, WvB, 960, 1024, 960, (long long)1024 * 960, 0, 4);
  cvt(Wq1, WqB, 64, 128, 64,   352256, 0,     4);
  cvt(Wq2, WqB, 128, 128, 128, 352256, 8192,  4);
  cvt(Wq3, WqB, 256, 256, 256, 352256, 24576, 4);
  cvt(Wq4, WqB, 512, 512, 512, 352256, 90112, 4);
  cvt(Wo1, WoB, 64, 128, 64,   0, 0,     1);
  cvt(Wo2, WoB, 128, 128, 128, 0, 8192,  1);
  cvt(Wo3, WoB, 256, 256, 256, 0, 24576, 1);
  cvt(Wo4, WoB, 512, 512, 512, 0, 90112, 1);

  const int NT = NB / 128;
  for (int b0 = 0; b0 < 32; b0 += Bc) {
    hipMemsetAsync(stats, 0, (size_t)Bc * 32 * 4, stream);
    k_kt<<<dim3(NT, 8, 4), blk, 0, stream>>>(embA, WkB, Kt, b0, NB);
    k_v <<<dim3(8, NT, 4), blk, 0, stream>>>(embA, WvB, V, b0, NB);
    k_q <<<dim3(NT, 8, 4), blk, 0, stream>>>(embA, WqB, Qt, b0, NB);
    k_s <<<dim3(8, 8, Bc * 4), blk, 0, stream>>>(Qt, Kt, S, stats, NB);
    k_sm<<<dim3(Bc * 960), blk, 0, stream>>>(S, stats);
    k_pv<<<dim3(8, 2, Bc * 4), blk, 0, stream>>>(V, S, ctxh);
    k_ctxred<<<dim3((Bc * 229376 / 8 + 255) / 256), blk, 0, stream>>>(ctxh, ctx, Bc);
    k_o <<<dim3(8, 2, Bc), blk, 0, stream>>>(ctx, WoB, out, b0);
  }
}